// Round 1
// baseline (4702.754 us; speedup 1.0000x reference)
//
#include <hip/hip_runtime.h>
#include <math.h>

// Problem constants
constexpr int NB = 32;      // batch
constexpr int NL = 32;      // sequence length L
constexpr int ND = 512;     // input dim D
constexpr int NHID = 512;   // hidden H
constexpr int NSTEPS = 31;  // L-1 merge steps
constexpr int KC = 1024;    // 2H (cell GEMM K)
constexpr int NC5 = 2560;   // 5H (cell GEMM N)
constexpr int BH = NB * NHID;      // 16384
constexpr int STATE_F = NL * BH;   // 524288 floats per state buffer

// Workspace layout (in floats). Total ~22.6 MB.
constexpr size_t OFF_H0 = 0;
constexpr size_t OFF_H1 = OFF_H0 + STATE_F;
constexpr size_t OFF_C0 = OFF_H1 + STATE_F;
constexpr size_t OFF_C1 = OFF_C0 + STATE_F;
constexpr size_t OFF_G  = OFF_C1 + STATE_F;                       // 31*32*2560
constexpr size_t OFF_NH = OFF_G  + (size_t)NSTEPS * NB * NC5;
constexpr size_t OFF_NC = OFF_NH + (size_t)NSTEPS * NB * NHID;
constexpr size_t OFF_LG = OFF_NC + (size_t)NSTEPS * NB * NHID;    // logits [b][j]
constexpr size_t OFF_ML = OFF_LG + 1024;                          // maxlen (int)

__device__ __forceinline__ float sigf(float x) { return 1.f / (1.f + expf(-x)); }

__global__ void prep_kernel(const int* __restrict__ len, int* __restrict__ maxlen) {
    if (threadIdx.x == 0) {
        int m = 2;
        for (int b = 0; b < NB; ++b) m = max(m, len[b]);
        *maxlen = m;
    }
}

// hc = inp @ W_word + b_word ; split into h0 (cols<512) and c0.
// Writes state buffers [l][b][h] and leaf nodes out[2BH + (b*63+l)*512 + h].
__global__ __launch_bounds__(256) void word_gemm(
    const float* __restrict__ A,     // inp (1024 x 512), row r = b*32+l
    const float* __restrict__ W,     // W_word (512 x 1024)
    const float* __restrict__ bias,  // b_word (1024)
    float* __restrict__ hst, float* __restrict__ cst,
    float* __restrict__ out)
{
    const int m0 = blockIdx.x * 128;
    const int n0 = blockIdx.y * 128;
    const int tid = threadIdx.x;
    const int tx = tid & 15, ty = tid >> 4;
    __shared__ float As[16][128];
    __shared__ float Bs[16][128];
    float acc[8][8];
#pragma unroll
    for (int i = 0; i < 8; ++i)
#pragma unroll
        for (int j = 0; j < 8; ++j) acc[i][j] = 0.f;

    for (int kt = 0; kt < ND; kt += 16) {
#pragma unroll
        for (int t = 0; t < 2; ++t) {
            int idx = tid + t * 256;
            int row = idx >> 2, kq = idx & 3;
            float4 v = *(const float4*)(A + (size_t)(m0 + row) * ND + kt + kq * 4);
            As[kq * 4 + 0][row] = v.x;
            As[kq * 4 + 1][row] = v.y;
            As[kq * 4 + 2][row] = v.z;
            As[kq * 4 + 3][row] = v.w;
        }
#pragma unroll
        for (int t = 0; t < 2; ++t) {
            int idx = tid + t * 256;
            int kr = idx >> 5, nq = idx & 31;
            float4 v = *(const float4*)(W + (size_t)(kt + kr) * 1024 + n0 + nq * 4);
            *(float4*)&Bs[kr][nq * 4] = v;
        }
        __syncthreads();
#pragma unroll
        for (int kk = 0; kk < 16; ++kk) {
            float av[8], bv[8];
            *(float4*)&av[0] = *(float4*)&As[kk][ty * 8];
            *(float4*)&av[4] = *(float4*)&As[kk][ty * 8 + 4];
            *(float4*)&bv[0] = *(float4*)&Bs[kk][tx * 8];
            *(float4*)&bv[4] = *(float4*)&Bs[kk][tx * 8 + 4];
#pragma unroll
            for (int mi = 0; mi < 8; ++mi)
#pragma unroll
                for (int ni = 0; ni < 8; ++ni)
                    acc[mi][ni] = fmaf(av[mi], bv[ni], acc[mi][ni]);
        }
        __syncthreads();
    }
    float* nodes = out + 2 * BH;
#pragma unroll
    for (int mi = 0; mi < 8; ++mi) {
        int r = m0 + ty * 8 + mi;
        int b = r >> 5, l = r & 31;
#pragma unroll
        for (int ni = 0; ni < 8; ++ni) {
            int n = n0 + tx * 8 + ni;
            float v = acc[mi][ni] + bias[n];
            if (n < NHID) {
                hst[(size_t)l * BH + b * NHID + n] = v;
                nodes[((size_t)b * 63 + l) * NHID + n] = v;  // leaves
            } else {
                cst[(size_t)l * BH + b * NHID + (n - NHID)] = v;
            }
        }
    }
}

// g[j][b][:] = [h[j][b], h[j+1][b]] @ W_comp + b_comp  for j < actmax
__global__ __launch_bounds__(256) void cell_gemm(
    const float* __restrict__ hst,   // state [l][b][h], l in 0..31
    const float* __restrict__ W,     // W_comp (1024 x 2560)
    const float* __restrict__ bias,  // b_comp (2560)
    float* __restrict__ g,           // [j][b][2560]
    const int* __restrict__ maxlen_p, int step)
{
    int actmax = *maxlen_p - 1 - step;
    if (actmax < 1) actmax = 1;
    const int m0 = blockIdx.x * 128;               // rows r = j*32 + b
    if (m0 >= actmax * NB) return;                 // trimmed j-tile
    const int n0 = blockIdx.y * 128;
    const int tid = threadIdx.x;
    const int tx = tid & 15, ty = tid >> 4;
    __shared__ float As[16][128];
    __shared__ float Bs[16][128];
    float acc[8][8];
#pragma unroll
    for (int i = 0; i < 8; ++i)
#pragma unroll
        for (int j = 0; j < 8; ++j) acc[i][j] = 0.f;

    for (int kt = 0; kt < KC; kt += 16) {
#pragma unroll
        for (int t = 0; t < 2; ++t) {
            int idx = tid + t * 256;
            int row = idx >> 2, kq = idx & 3;
            int r = m0 + row;
            int j = r >> 5, b = r & 31;
            int jc = min(j, 30);                    // clamp invalid tail rows
            int k = kt + kq * 4;
            const float* src = hst + (size_t)(k < NHID ? jc : jc + 1) * BH
                             + b * NHID + (k & (NHID - 1));
            float4 v = *(const float4*)src;
            As[kq * 4 + 0][row] = v.x;
            As[kq * 4 + 1][row] = v.y;
            As[kq * 4 + 2][row] = v.z;
            As[kq * 4 + 3][row] = v.w;
        }
#pragma unroll
        for (int t = 0; t < 2; ++t) {
            int idx = tid + t * 256;
            int kr = idx >> 5, nq = idx & 31;
            float4 v = *(const float4*)(W + (size_t)(kt + kr) * NC5 + n0 + nq * 4);
            *(float4*)&Bs[kr][nq * 4] = v;
        }
        __syncthreads();
#pragma unroll
        for (int kk = 0; kk < 16; ++kk) {
            float av[8], bv[8];
            *(float4*)&av[0] = *(float4*)&As[kk][ty * 8];
            *(float4*)&av[4] = *(float4*)&As[kk][ty * 8 + 4];
            *(float4*)&bv[0] = *(float4*)&Bs[kk][tx * 8];
            *(float4*)&bv[4] = *(float4*)&Bs[kk][tx * 8 + 4];
#pragma unroll
            for (int mi = 0; mi < 8; ++mi)
#pragma unroll
                for (int ni = 0; ni < 8; ++ni)
                    acc[mi][ni] = fmaf(av[mi], bv[ni], acc[mi][ni]);
        }
        __syncthreads();
    }
    float bv8[8];
#pragma unroll
    for (int ni = 0; ni < 8; ++ni) bv8[ni] = bias[n0 + tx * 8 + ni];
#pragma unroll
    for (int mi = 0; mi < 8; ++mi) {
        int r = m0 + ty * 8 + mi;
        int j = r >> 5, b = r & 31;
        if (j >= actmax) continue;                 // also excludes j==31 tail
        float* dst = g + (size_t)(j * NB + b) * NC5 + n0 + tx * 8;
        float o[8];
#pragma unroll
        for (int ni = 0; ni < 8; ++ni) o[ni] = acc[mi][ni] + bv8[ni];
        *(float4*)&dst[0] = *(const float4*)&o[0];
        *(float4*)&dst[4] = *(const float4*)&o[4];
    }
}

// activations + logits (per (j,b) row). nh/nc [j][b][h], logits [b][j].
__global__ __launch_bounds__(256) void act_logits(
    const float* __restrict__ g, const float* __restrict__ cst,
    const float* __restrict__ q,
    float* __restrict__ nh, float* __restrict__ nc, float* __restrict__ logits,
    const int* __restrict__ maxlen_p, int step)
{
    int actmax = *maxlen_p - 1 - step;
    if (actmax < 1) actmax = 1;
    const int j = blockIdx.x;
    if (j >= actmax) return;
    const int b = blockIdx.y;
    const float* grow = g + (size_t)(j * NB + b) * NC5;
    const float* clrow = cst + (size_t)j * BH + b * NHID;
    const float* crrow = clrow + BH;
    float part = 0.f;
    for (int h = threadIdx.x; h < NHID; h += 256) {
        float ig = grow[h];
        float fl = grow[NHID + h];
        float fr = grow[2 * NHID + h];
        float u  = grow[3 * NHID + h];
        float o  = grow[4 * NHID + h];
        float cl = clrow[h], cr = crrow[h];
        float c  = cl * sigf(fl + 1.f) + cr * sigf(fr + 1.f) + tanhf(u) * sigf(ig);
        float hh = sigf(o) * tanhf(c);
        nh[(size_t)(j * NB + b) * NHID + h] = hh;
        nc[(size_t)(j * NB + b) * NHID + h] = c;
        part = fmaf(hh, q[h], part);
    }
#pragma unroll
    for (int off = 32; off > 0; off >>= 1) part += __shfl_down(part, off);
    __shared__ float red[4];
    if ((threadIdx.x & 63) == 0) red[threadIdx.x >> 6] = part;
    __syncthreads();
    if (threadIdx.x == 0) logits[b * NSTEPS + j] = red[0] + red[1] + red[2] + red[3];
}

// Per-(b, j) block: argmax (redundant per block, cheap), ping-pong state
// merge/copy, node + final hf/cf writes (block j==0).
__global__ __launch_bounds__(256) void update_kernel(
    const float* __restrict__ logits, const int* __restrict__ len,
    const float* __restrict__ nh, const float* __restrict__ nc,
    const float* __restrict__ hcur, const float* __restrict__ ccur,
    float* __restrict__ hnxt, float* __restrict__ cnxt,
    float* __restrict__ out, int step)
{
    const int b = blockIdx.x;
    const int j = blockIdx.y;  // 0..31 state rows
    const int tid = threadIdx.x;
    __shared__ int sk, smerge;
    if (tid < 64) {
        int actb = len[b] - 1 - step;
        float v = -1e30f;
        int idx = tid;
        if (tid < NSTEPS && tid < actb) v = logits[b * NSTEPS + tid];
#pragma unroll
        for (int off = 32; off > 0; off >>= 1) {
            float ov = __shfl_down(v, off);
            int   oi = __shfl_down(idx, off);
            if (ov > v || (ov == v && oi < idx)) { v = ov; idx = oi; }
        }
        if (tid == 0) { sk = idx; smerge = (actb >= 1) ? 1 : 0; }
    }
    __syncthreads();
    const int k = sk, merge = smerge;
    const int last = (step == NSTEPS - 1);

    // state into next buffer (exact reference semantics incl. junk rows)
    int srcj = j, useNew = 0, zero = 0;
    if (merge) {
        if (j == k) useNew = 1;
        else if (j > k) { srcj = j + 1; if (srcj > NL - 1) zero = 1; }
    }
    for (int h = tid; h < NHID; h += 256) {
        float hv, cv;
        if (zero)        { hv = 0.f; cv = 0.f; }
        else if (useNew) { hv = nh[(size_t)(k * NB + b) * NHID + h];
                           cv = nc[(size_t)(k * NB + b) * NHID + h]; }
        else             { hv = hcur[(size_t)srcj * BH + b * NHID + h];
                           cv = ccur[(size_t)srcj * BH + b * NHID + h]; }
        hnxt[(size_t)j * BH + b * NHID + h] = hv;
        cnxt[(size_t)j * BH + b * NHID + h] = cv;
    }

    if (j == 0) {
        float* hf = out;
        float* cf = out + BH;
        float* noderow = out + 2 * BH + ((size_t)b * 63 + 32 + step) * NHID;
        for (int h = tid; h < NHID; h += 256) {
            float nodev;
            if (!last) {
                nodev = merge ? nh[(size_t)(k * NB + b) * NHID + h]
                              : nh[(size_t)b * NHID + h];
            } else {
                nodev = merge ? nh[(size_t)b * NHID + h]
                              : hcur[(size_t)b * NHID + h];
                hf[b * NHID + h] = nodev;
                cf[b * NHID + h] = merge ? nc[(size_t)b * NHID + h]
                                         : ccur[(size_t)b * NHID + h];
            }
            noderow[h] = nodev;
        }
    }
}

extern "C" void kernel_launch(void* const* d_in, const int* in_sizes, int n_in,
                              void* d_out, int out_size, void* d_ws, size_t ws_size,
                              hipStream_t stream) {
    const float* inp    = (const float*)d_in[0];
    const int*   length = (const int*)d_in[1];
    const float* W_word = (const float*)d_in[2];
    const float* b_word = (const float*)d_in[3];
    const float* W_comp = (const float*)d_in[4];
    const float* b_comp = (const float*)d_in[5];
    const float* q      = (const float*)d_in[6];
    float* out = (float*)d_out;
    float* ws  = (float*)d_ws;

    float* hbuf[2] = { ws + OFF_H0, ws + OFF_H1 };
    float* cbuf[2] = { ws + OFF_C0, ws + OFF_C1 };
    float* g       = ws + OFF_G;
    float* nh      = ws + OFF_NH;
    float* nc      = ws + OFF_NC;
    float* logits  = ws + OFF_LG;
    int*   maxlen  = (int*)(ws + OFF_ML);

    prep_kernel<<<1, 64, 0, stream>>>(length, maxlen);
    word_gemm<<<dim3(8, 8), 256, 0, stream>>>(inp, W_word, b_word,
                                              hbuf[0], cbuf[0], out);
    for (int i = 0; i < NSTEPS; ++i) {
        int cur = i & 1, nxt = cur ^ 1;
        cell_gemm<<<dim3(8, 20), 256, 0, stream>>>(hbuf[cur], W_comp, b_comp,
                                                   g, maxlen, i);
        act_logits<<<dim3(NSTEPS, NB), 256, 0, stream>>>(g, cbuf[cur], q,
                                                         nh, nc, logits, maxlen, i);
        update_kernel<<<dim3(NB, NL), 256, 0, stream>>>(logits, length, nh, nc,
                                                        hbuf[cur], cbuf[cur],
                                                        hbuf[nxt], cbuf[nxt],
                                                        out, i);
    }
}

// Round 2
// 1454.863 us; speedup vs baseline: 3.2324x; 3.2324x over previous
//
#include <hip/hip_runtime.h>
#include <math.h>

// Problem constants
constexpr int NB = 32, NL = 32, ND = 512, NHID = 512, NSTEPS = 31;
constexpr int KC = 1024;    // 2H
constexpr int NC5 = 2560;   // 5H
constexpr int BH = NB * NHID;          // 16384
constexpr int STATE_F = NL * BH;       // 524288 floats (c state)
constexpr int STATE_H = NL * NB * NHID;// 524288 halves per split plane

// Workspace layout (float offsets). Total ~33 MB.
constexpr size_t OFF_C0  = 0;
constexpr size_t OFF_C1  = OFF_C0 + STATE_F;
constexpr size_t OFF_G   = OFF_C1 + STATE_F;                      // 31*32*2560 f32
constexpr size_t OFF_NH  = OFF_G  + (size_t)NSTEPS * NB * NC5;
constexpr size_t OFF_NC  = OFF_NH + (size_t)NSTEPS * NB * NHID;
constexpr size_t OFF_LG  = OFF_NC + (size_t)NSTEPS * NB * NHID;
constexpr size_t OFF_ML  = OFF_LG + 1024;
constexpr size_t OFF_HI0 = OFF_ML + 64;                // halves planes, 262144 floats each
constexpr size_t OFF_HI1 = OFF_HI0 + STATE_H / 2;
constexpr size_t OFF_LO0 = OFF_HI1 + STATE_H / 2;
constexpr size_t OFF_LO1 = OFF_LO0 + STATE_H / 2;
constexpr size_t OFF_WTH = OFF_LO1 + STATE_H / 2;      // W_comp^T hi plane [n][k] halves
constexpr size_t OFF_WTL = OFF_WTH + (size_t)NC5 * KC / 2;

typedef _Float16 half8 __attribute__((ext_vector_type(8)));
typedef _Float16 half4 __attribute__((ext_vector_type(4)));
typedef float    f32x4 __attribute__((ext_vector_type(4)));

constexpr float INV2048 = 1.f / 2048.f;

__device__ __forceinline__ float sigf(float x) { return 1.f / (1.f + expf(-x)); }

__global__ void prep_kernel(const int* __restrict__ len, int* __restrict__ maxlen) {
    if (threadIdx.x == 0) {
        int m = 2;
        for (int b = 0; b < NB; ++b) m = max(m, len[b]);
        *maxlen = m;
    }
}

// W_comp (1024 x 2560 f32) -> transposed split planes Wth/Wtl [n][k] fp16.
// lo plane scaled by 2^11 so it stays in fp16 normal range.
__global__ __launch_bounds__(256) void wsplit_kernel(
    const float* __restrict__ W, _Float16* __restrict__ Wth, _Float16* __restrict__ Wtl)
{
    __shared__ float t[32][33];
    const int n0 = blockIdx.x * 32, k0 = blockIdx.y * 32;
    const int tid = threadIdx.x;
    const int c = tid & 31, r8 = tid >> 5;
#pragma unroll
    for (int p = 0; p < 4; ++p) {
        int r = p * 8 + r8;
        t[r][c] = W[(size_t)(k0 + r) * NC5 + n0 + c];
    }
    __syncthreads();
    const int nl = tid >> 3, k4 = (tid & 7) * 4;
    half4 vh, vl;
#pragma unroll
    for (int i = 0; i < 4; ++i) {
        float v = t[k4 + i][nl];
        _Float16 hh = (_Float16)v;
        vh[i] = hh;
        vl[i] = (_Float16)((v - (float)hh) * 2048.f);
    }
    size_t o = (size_t)(n0 + nl) * KC + k0 + k4;
    *(half4*)&Wth[o] = vh;
    *(half4*)&Wtl[o] = vl;
}

// hc = inp @ W_word + b_word. 64x64 f32 tile, 4x4/thread, grid 16x16 (256 blocks).
// n<512 -> h state written as split fp16 planes + f32 leaf nodes; n>=512 -> c f32.
__global__ __launch_bounds__(256) void word_gemm64(
    const float* __restrict__ A, const float* __restrict__ W,
    const float* __restrict__ bias,
    _Float16* __restrict__ hi0, _Float16* __restrict__ lo0,
    float* __restrict__ cst, float* __restrict__ out)
{
    const int m0 = blockIdx.x * 64;
    const int n0 = blockIdx.y * 64;
    const int tid = threadIdx.x;
    const int tx = tid & 15, ty = tid >> 4;
    __shared__ float As[16][64];
    __shared__ float Bs[16][64];
    float acc[4][4];
#pragma unroll
    for (int i = 0; i < 4; ++i)
#pragma unroll
        for (int j = 0; j < 4; ++j) acc[i][j] = 0.f;

    for (int kt = 0; kt < ND; kt += 16) {
        {
            int row = tid >> 2, kq = tid & 3;
            float4 v = *(const float4*)(A + (size_t)(m0 + row) * ND + kt + kq * 4);
            As[kq * 4 + 0][row] = v.x;
            As[kq * 4 + 1][row] = v.y;
            As[kq * 4 + 2][row] = v.z;
            As[kq * 4 + 3][row] = v.w;
            int kr = tid >> 4, nq = tid & 15;
            float4 vb = *(const float4*)(W + (size_t)(kt + kr) * 1024 + n0 + nq * 4);
            *(float4*)&Bs[kr][nq * 4] = vb;
        }
        __syncthreads();
#pragma unroll
        for (int kk = 0; kk < 16; ++kk) {
            float a0 = As[kk][ty * 4 + 0], a1 = As[kk][ty * 4 + 1];
            float a2 = As[kk][ty * 4 + 2], a3 = As[kk][ty * 4 + 3];
            float4 bv = *(float4*)&Bs[kk][tx * 4];
            acc[0][0] = fmaf(a0, bv.x, acc[0][0]); acc[0][1] = fmaf(a0, bv.y, acc[0][1]);
            acc[0][2] = fmaf(a0, bv.z, acc[0][2]); acc[0][3] = fmaf(a0, bv.w, acc[0][3]);
            acc[1][0] = fmaf(a1, bv.x, acc[1][0]); acc[1][1] = fmaf(a1, bv.y, acc[1][1]);
            acc[1][2] = fmaf(a1, bv.z, acc[1][2]); acc[1][3] = fmaf(a1, bv.w, acc[1][3]);
            acc[2][0] = fmaf(a2, bv.x, acc[2][0]); acc[2][1] = fmaf(a2, bv.y, acc[2][1]);
            acc[2][2] = fmaf(a2, bv.z, acc[2][2]); acc[2][3] = fmaf(a2, bv.w, acc[2][3]);
            acc[3][0] = fmaf(a3, bv.x, acc[3][0]); acc[3][1] = fmaf(a3, bv.y, acc[3][1]);
            acc[3][2] = fmaf(a3, bv.z, acc[3][2]); acc[3][3] = fmaf(a3, bv.w, acc[3][3]);
        }
        __syncthreads();
    }
    float* nodes = out + 2 * BH;
#pragma unroll
    for (int i = 0; i < 4; ++i) {
        int r = m0 + ty * 4 + i;
        int b = r >> 5, l = r & 31;
#pragma unroll
        for (int jn = 0; jn < 4; ++jn) {
            int n = n0 + tx * 4 + jn;
            float v = acc[i][jn] + bias[n];
            if (n < NHID) {
                size_t si = ((size_t)l * NB + b) * NHID + n;
                _Float16 hh = (_Float16)v;
                hi0[si] = hh;
                lo0[si] = (_Float16)((v - (float)hh) * 2048.f);
                nodes[((size_t)b * 63 + l) * NHID + n] = v;
            } else {
                cst[((size_t)l * NB + b) * NHID + (n - NHID)] = v;
            }
        }
    }
}

// Split-fp16 MFMA cell GEMM: g[j][b][:] = [h[j],h[j+1]] @ W_comp + b_comp.
// 64x64 block tile, 4 waves of 32x32 (2x2 MFMA 16x16x32_f16 tiles x 3 products).
// C = acc1 + acc2/2048 (acc1 = Ah*Bh, acc2 = Ah*Bl' + Al'*Bh, lo scaled 2^11).
__global__ __launch_bounds__(256) void cell_gemm_mfma(
    const _Float16* __restrict__ hi, const _Float16* __restrict__ lo,
    const _Float16* __restrict__ Wth, const _Float16* __restrict__ Wtl,
    const float* __restrict__ bias, float* __restrict__ g,
    const int* __restrict__ maxlen_p, int step)
{
    int actmax = *maxlen_p - 1 - step;
    if (actmax < 1) actmax = 1;
    const int m0 = blockIdx.x * 64;
    if (m0 >= actmax * NB) return;
    const int n0 = blockIdx.y * 64;

    // LDS: [plane][row][k] pitch 40 halves (80 B) -> 2-way bank aliasing only.
    __shared__ __align__(16) _Float16 sA[2][64 * 40];
    __shared__ __align__(16) _Float16 sB[2][64 * 40];

    const int tid = threadIdx.x;
    const int wave = tid >> 6, lane = tid & 63;
    const int wm = wave & 1, wn = wave >> 1;
    const int lm = lane & 15, lq = lane >> 4;

    // staging: thread -> (row, 16B quarter of the 32-halves k-chunk)
    const int srow = tid >> 2, sq = tid & 3;
    {
        // nothing
    }
    int m = m0 + srow;
    int jr = m >> 5, br = m & 31;
    int jc = min(jr, 30);
    const _Float16* aHi0 = hi + ((size_t)jc * NB + br) * NHID;
    const _Float16* aHi1 = hi + ((size_t)(jc + 1) * NB + br) * NHID;
    const _Float16* aLo0 = lo + ((size_t)jc * NB + br) * NHID;
    const _Float16* aLo1 = lo + ((size_t)(jc + 1) * NB + br) * NHID;
    const _Float16* bHi = Wth + (size_t)(n0 + srow) * KC;
    const _Float16* bLo = Wtl + (size_t)(n0 + srow) * KC;

    f32x4 acc1[2][2], acc2[2][2];
#pragma unroll
    for (int i = 0; i < 2; ++i)
#pragma unroll
        for (int j = 0; j < 2; ++j) { acc1[i][j] = (f32x4)0.f; acc2[i][j] = (f32x4)0.f; }

    _Float16* wA0 = &sA[0][srow * 40 + sq * 8];
    _Float16* wA1 = &sA[1][srow * 40 + sq * 8];
    _Float16* wB0 = &sB[0][srow * 40 + sq * 8];
    _Float16* wB1 = &sB[1][srow * 40 + sq * 8];

    const int a0off = (wm * 32 + lm) * 40 + lq * 8;        // msub 0
    const int a1off = (wm * 32 + 16 + lm) * 40 + lq * 8;   // msub 1
    const int b0off = (wn * 32 + lm) * 40 + lq * 8;
    const int b1off = (wn * 32 + 16 + lm) * 40 + lq * 8;

    for (int kt = 0; kt < KC; kt += 32) {
        int kb = kt + sq * 8;
        const _Float16* pah = (kb < NHID) ? (aHi0 + kb) : (aHi1 + (kb - NHID));
        const _Float16* pal = (kb < NHID) ? (aLo0 + kb) : (aLo1 + (kb - NHID));
        uint4 vah = *(const uint4*)pah;
        uint4 val = *(const uint4*)pal;
        uint4 vbh = *(const uint4*)(bHi + kb);
        uint4 vbl = *(const uint4*)(bLo + kb);
        __syncthreads();
        *(uint4*)wA0 = vah;
        *(uint4*)wA1 = val;
        *(uint4*)wB0 = vbh;
        *(uint4*)wB1 = vbl;
        __syncthreads();

        half8 Ah0 = *(half8*)&sA[0][a0off];
        half8 Ah1 = *(half8*)&sA[0][a1off];
        half8 Al0 = *(half8*)&sA[1][a0off];
        half8 Al1 = *(half8*)&sA[1][a1off];
        half8 Bh0 = *(half8*)&sB[0][b0off];
        half8 Bh1 = *(half8*)&sB[0][b1off];
        half8 Bl0 = *(half8*)&sB[1][b0off];
        half8 Bl1 = *(half8*)&sB[1][b1off];

        acc1[0][0] = __builtin_amdgcn_mfma_f32_16x16x32_f16(Ah0, Bh0, acc1[0][0], 0, 0, 0);
        acc1[0][1] = __builtin_amdgcn_mfma_f32_16x16x32_f16(Ah0, Bh1, acc1[0][1], 0, 0, 0);
        acc1[1][0] = __builtin_amdgcn_mfma_f32_16x16x32_f16(Ah1, Bh0, acc1[1][0], 0, 0, 0);
        acc1[1][1] = __builtin_amdgcn_mfma_f32_16x16x32_f16(Ah1, Bh1, acc1[1][1], 0, 0, 0);
        acc2[0][0] = __builtin_amdgcn_mfma_f32_16x16x32_f16(Ah0, Bl0, acc2[0][0], 0, 0, 0);
        acc2[0][1] = __builtin_amdgcn_mfma_f32_16x16x32_f16(Ah0, Bl1, acc2[0][1], 0, 0, 0);
        acc2[1][0] = __builtin_amdgcn_mfma_f32_16x16x32_f16(Ah1, Bl0, acc2[1][0], 0, 0, 0);
        acc2[1][1] = __builtin_amdgcn_mfma_f32_16x16x32_f16(Ah1, Bl1, acc2[1][1], 0, 0, 0);
        acc2[0][0] = __builtin_amdgcn_mfma_f32_16x16x32_f16(Al0, Bh0, acc2[0][0], 0, 0, 0);
        acc2[0][1] = __builtin_amdgcn_mfma_f32_16x16x32_f16(Al0, Bh1, acc2[0][1], 0, 0, 0);
        acc2[1][0] = __builtin_amdgcn_mfma_f32_16x16x32_f16(Al1, Bh0, acc2[1][0], 0, 0, 0);
        acc2[1][1] = __builtin_amdgcn_mfma_f32_16x16x32_f16(Al1, Bh1, acc2[1][1], 0, 0, 0);
    }

    // Epilogue. C/D layout: col = lane&15, row = (lane>>4)*4 + reg.
#pragma unroll
    for (int ms = 0; ms < 2; ++ms) {
#pragma unroll
        for (int ns = 0; ns < 2; ++ns) {
            int nn = n0 + wn * 32 + ns * 16 + lm;
            float bn = bias[nn];
            int mbase = m0 + wm * 32 + ms * 16 + lq * 4;
#pragma unroll
            for (int r = 0; r < 4; ++r) {
                int mrow = mbase + r;
                int jj = mrow >> 5, bb = mrow & 31;
                if (jj < actmax) {
                    g[((size_t)jj * NB + bb) * NC5 + nn] =
                        acc1[ms][ns][r] + acc2[ms][ns][r] * INV2048 + bn;
                }
            }
        }
    }
}

// activations + logits (per (j,b) row). nh/nc [j][b][h], logits [b][j].
__global__ __launch_bounds__(256) void act_logits(
    const float* __restrict__ g, const float* __restrict__ cst,
    const float* __restrict__ q,
    float* __restrict__ nh, float* __restrict__ nc, float* __restrict__ logits,
    const int* __restrict__ maxlen_p, int step)
{
    int actmax = *maxlen_p - 1 - step;
    if (actmax < 1) actmax = 1;
    const int j = blockIdx.x;
    if (j >= actmax) return;
    const int b = blockIdx.y;
    const float* grow = g + (size_t)(j * NB + b) * NC5;
    const float* clrow = cst + (size_t)j * BH + b * NHID;
    const float* crrow = clrow + BH;
    float part = 0.f;
    for (int h = threadIdx.x; h < NHID; h += 256) {
        float ig = grow[h];
        float fl = grow[NHID + h];
        float fr = grow[2 * NHID + h];
        float u  = grow[3 * NHID + h];
        float o  = grow[4 * NHID + h];
        float cl = clrow[h], cr = crrow[h];
        float c  = cl * sigf(fl + 1.f) + cr * sigf(fr + 1.f) + tanhf(u) * sigf(ig);
        float hh = sigf(o) * tanhf(c);
        nh[(size_t)(j * NB + b) * NHID + h] = hh;
        nc[(size_t)(j * NB + b) * NHID + h] = c;
        part = fmaf(hh, q[h], part);
    }
#pragma unroll
    for (int off = 32; off > 0; off >>= 1) part += __shfl_down(part, off);
    __shared__ float red[4];
    if ((threadIdx.x & 63) == 0) red[threadIdx.x >> 6] = part;
    __syncthreads();
    if (threadIdx.x == 0) logits[b * NSTEPS + j] = red[0] + red[1] + red[2] + red[3];
}

// Per-(b, j) block: argmax, ping-pong state merge/copy (split-fp16 h, f32 c),
// node + final hf/cf writes (block j==0).
__global__ __launch_bounds__(256) void update_kernel(
    const float* __restrict__ logits, const int* __restrict__ len,
    const float* __restrict__ nh, const float* __restrict__ nc,
    const _Float16* __restrict__ hiC, const _Float16* __restrict__ loC,
    const float* __restrict__ cC,
    _Float16* __restrict__ hiN, _Float16* __restrict__ loN,
    float* __restrict__ cN,
    float* __restrict__ out, int step)
{
    const int b = blockIdx.x;
    const int j = blockIdx.y;
    const int tid = threadIdx.x;
    __shared__ int sk, smerge;
    if (tid < 64) {
        int actb = len[b] - 1 - step;
        float v = -1e30f;
        int idx = tid;
        if (tid < NSTEPS && tid < actb) v = logits[b * NSTEPS + tid];
#pragma unroll
        for (int off = 32; off > 0; off >>= 1) {
            float ov = __shfl_down(v, off);
            int   oi = __shfl_down(idx, off);
            if (ov > v || (ov == v && oi < idx)) { v = ov; idx = oi; }
        }
        if (tid == 0) { sk = idx; smerge = (actb >= 1) ? 1 : 0; }
    }
    __syncthreads();
    const int k = sk, merge = smerge;
    const int last = (step == NSTEPS - 1);

    int srcj = j, useNew = 0, zero = 0;
    if (merge) {
        if (j == k) useNew = 1;
        else if (j > k) { srcj = j + 1; if (srcj > NL - 1) zero = 1; }
    }
    for (int h = tid; h < NHID; h += 256) {
        _Float16 hh, hl; float cv;
        if (zero) { hh = (_Float16)0.f; hl = (_Float16)0.f; cv = 0.f; }
        else if (useNew) {
            float x = nh[((size_t)k * NB + b) * NHID + h];
            hh = (_Float16)x;
            hl = (_Float16)((x - (float)hh) * 2048.f);
            cv = nc[((size_t)k * NB + b) * NHID + h];
        } else {
            size_t si = ((size_t)srcj * NB + b) * NHID + h;
            hh = hiC[si]; hl = loC[si]; cv = cC[si];
        }
        size_t di = ((size_t)j * NB + b) * NHID + h;
        hiN[di] = hh; loN[di] = hl; cN[di] = cv;
    }

    if (j == 0) {
        float* hf = out;
        float* cf = out + BH;
        float* noderow = out + 2 * BH + ((size_t)b * 63 + 32 + step) * NHID;
        for (int h = tid; h < NHID; h += 256) {
            float nodev;
            if (!last) {
                nodev = merge ? nh[((size_t)k * NB + b) * NHID + h]
                              : nh[(size_t)b * NHID + h];
            } else {
                if (merge) {
                    nodev = nh[(size_t)b * NHID + h];
                    hf[b * NHID + h] = nodev;
                    cf[b * NHID + h] = nc[(size_t)b * NHID + h];
                } else {
                    size_t si = (size_t)b * NHID + h;  // j==0 row
                    nodev = (float)hiC[si] + (float)loC[si] * INV2048;
                    hf[b * NHID + h] = nodev;
                    cf[b * NHID + h] = cC[si];
                }
            }
            noderow[h] = nodev;
        }
    }
}

extern "C" void kernel_launch(void* const* d_in, const int* in_sizes, int n_in,
                              void* d_out, int out_size, void* d_ws, size_t ws_size,
                              hipStream_t stream) {
    const float* inp    = (const float*)d_in[0];
    const int*   length = (const int*)d_in[1];
    const float* W_word = (const float*)d_in[2];
    const float* b_word = (const float*)d_in[3];
    const float* W_comp = (const float*)d_in[4];
    const float* b_comp = (const float*)d_in[5];
    const float* q      = (const float*)d_in[6];
    float* out = (float*)d_out;
    float* ws  = (float*)d_ws;

    float*     cbuf[2] = { ws + OFF_C0, ws + OFF_C1 };
    _Float16*  hbuf[2] = { (_Float16*)(ws + OFF_HI0), (_Float16*)(ws + OFF_HI1) };
    _Float16*  lbuf[2] = { (_Float16*)(ws + OFF_LO0), (_Float16*)(ws + OFF_LO1) };
    float*     g       = ws + OFF_G;
    float*     nh      = ws + OFF_NH;
    float*     nc      = ws + OFF_NC;
    float*     logits  = ws + OFF_LG;
    int*       maxlen  = (int*)(ws + OFF_ML);
    _Float16*  Wth     = (_Float16*)(ws + OFF_WTH);
    _Float16*  Wtl     = (_Float16*)(ws + OFF_WTL);

    prep_kernel<<<1, 64, 0, stream>>>(length, maxlen);
    wsplit_kernel<<<dim3(NC5 / 32, KC / 32), 256, 0, stream>>>(W_comp, Wth, Wtl);
    word_gemm64<<<dim3(16, 16), 256, 0, stream>>>(inp, W_word, b_word,
                                                  hbuf[0], lbuf[0], cbuf[0], out);
    for (int i = 0; i < NSTEPS; ++i) {
        int cur = i & 1, nxt = cur ^ 1;
        cell_gemm_mfma<<<dim3(16, 40), 256, 0, stream>>>(hbuf[cur], lbuf[cur],
                                                         Wth, Wtl, b_comp, g,
                                                         maxlen, i);
        act_logits<<<dim3(NSTEPS, NB), 256, 0, stream>>>(g, cbuf[cur], q,
                                                         nh, nc, logits, maxlen, i);
        update_kernel<<<dim3(NB, NL), 256, 0, stream>>>(logits, length, nh, nc,
                                                        hbuf[cur], lbuf[cur], cbuf[cur],
                                                        hbuf[nxt], lbuf[nxt], cbuf[nxt],
                                                        out, i);
    }
}